// Round 3
// baseline (797.882 us; speedup 1.0000x reference)
//
#include <hip/hip_runtime.h>
#include <math.h>

#define N_NODES 50000
#define N_EDGES 800000
#define N_GRAPHS 512
#define IN_DIM 126
#define DIM_H 128
#define BN_EPS 1e-5f
#define NBUCK 98  // dst >> 9 -> 98 buckets of 512 nodes

typedef unsigned int u32;
typedef short short8 __attribute__((ext_vector_type(8)));
typedef float f32x4 __attribute__((ext_vector_type(4)));

__device__ __forceinline__ unsigned short f2bf(float f) {
    u32 u = __float_as_uint(f);
    u += 0x7fffu + ((u >> 16) & 1u);  // RNE
    return (unsigned short)(u >> 16);
}
__device__ __forceinline__ float bflo(u32 u) { return __uint_as_float(u << 16); }
__device__ __forceinline__ float bfhi(u32 u) { return __uint_as_float(u & 0xffff0000u); }
__device__ __forceinline__ u32 pack2(float a, float b) {
    return (u32)f2bf(a) | ((u32)f2bf(b) << 16);
}

// ---------------- pad x [50000,126] fp32 -> A [50000,128] bf16 ----------------
__global__ void pad_x_kernel(const float* __restrict__ x, unsigned short* __restrict__ A) {
    int tid = blockIdx.x * blockDim.x + threadIdx.x;
    int n = tid >> 6, c2 = tid & 63;
    if (n >= N_NODES) return;
    int c = c2 * 2;
    float f0 = (c < IN_DIM) ? x[n * IN_DIM + c] : 0.f;
    float f1 = (c + 1 < IN_DIM) ? x[n * IN_DIM + c + 1] : 0.f;
    ((u32*)A)[tid] = pack2(f0, f1);
}

// ---------------- bucketed CSR build ----------------
// A1: per-block LDS histogram of dst>>9 -> global bucket_count
__global__ void bucket_count_kernel(const int* __restrict__ dst, int* __restrict__ bucket_count) {
    __shared__ int hist[NBUCK];
    int b = blockIdx.x, t = threadIdx.x;
    if (t < NBUCK) hist[t] = 0;
    __syncthreads();
    int e0 = b * 3125;
    for (int i = t; i < 3125; i += 256) atomicAdd(&hist[dst[e0 + i] >> 9], 1);
    __syncthreads();
    if (t < NBUCK && hist[t]) atomicAdd(&bucket_count[t], hist[t]);
}

// A2: scan 98 bucket counts -> bucket_base (99 entries), init bucket_cursor
__global__ void bucket_scan_kernel(const int* __restrict__ bucket_count,
                                   int* __restrict__ bucket_base, int* __restrict__ bucket_cursor) {
    __shared__ int s[128];
    int t = threadIdx.x;
    int v = (t < NBUCK) ? bucket_count[t] : 0;
    s[t] = v;
    __syncthreads();
    for (int d = 1; d < 128; d <<= 1) {
        int add = (t >= d) ? s[t - d] : 0;
        __syncthreads();
        s[t] += add;
        __syncthreads();
    }
    if (t < NBUCK) {
        int excl = s[t] - v;
        bucket_base[t] = excl;
        bucket_cursor[t] = excl;
        if (t == NBUCK - 1) bucket_base[NBUCK] = s[t];
    }
}

// A3: scatter (src,dst) pairs into block-reserved contiguous runs per bucket
__global__ void bucket_scatter_kernel(const int* __restrict__ src, const int* __restrict__ dst,
                                      int* __restrict__ bucket_cursor, uint2* __restrict__ ebuf) {
    __shared__ int hist[NBUCK], base[NBUCK];
    int b = blockIdx.x, t = threadIdx.x;
    if (t < NBUCK) hist[t] = 0;
    __syncthreads();
    int e0 = b * 3125;
    for (int i = t; i < 3125; i += 256) atomicAdd(&hist[dst[e0 + i] >> 9], 1);
    __syncthreads();
    if (t < NBUCK && hist[t]) base[t] = atomicAdd(&bucket_cursor[t], hist[t]);
    __syncthreads();
    if (t < NBUCK) hist[t] = 0;  // reuse as running cursor
    __syncthreads();
    for (int i = t; i < 3125; i += 256) {
        int s = src[e0 + i], d = dst[e0 + i];
        int k = d >> 9;
        int p = base[k] + atomicAdd(&hist[k], 1);
        ebuf[p] = make_uint2((u32)s, (u32)d);
    }
}

// B: one block per bucket: LDS hist + scan -> counts/offsets, scatter perm locally
__global__ __launch_bounds__(512) void bucket_build_kernel(
    const uint2* __restrict__ ebuf, const int* __restrict__ bucket_base,
    int* __restrict__ counts, int* __restrict__ offsets, int* __restrict__ perm) {
    __shared__ int hist[512], ex[512];
    int k = blockIdx.x, t = threadIdx.x;
    int nb = k << 9;
    int bb = bucket_base[k], bcnt = bucket_base[k + 1] - bb;
    hist[t] = 0;
    __syncthreads();
    for (int e = t; e < bcnt; e += 512) atomicAdd(&hist[(int)ebuf[bb + e].y - nb], 1);
    __syncthreads();
    int v = hist[t];
    ex[t] = v;
    __syncthreads();
    for (int d = 1; d < 512; d <<= 1) {
        int add = (t >= d) ? ex[t - d] : 0;
        __syncthreads();
        ex[t] += add;
        __syncthreads();
    }
    int excl = ex[t] - v;  // exclusive scan
    int node = nb + t;
    if (node < N_NODES) {
        counts[node] = v;
        offsets[node] = bb + excl;
    }
    __syncthreads();
    hist[t] = excl;  // reuse as running cursor (bucket-relative)
    __syncthreads();
    for (int e = t; e < bcnt; e += 512) {
        uint2 ed = ebuf[bb + e];
        int p = atomicAdd(&hist[(int)ed.y - nb], 1);
        perm[bb + p] = (int)ed.x;
    }
}

// ---------------- aggregate: y[n] = h[n] + sum_{e: dst=n} h[src(e)]  (bf16 rows) ----------
// one wave per node; quarter-wave q, 4 uint4 loads in flight (16 edges/iter)
__global__ void aggregate_kernel(const unsigned short* __restrict__ h,
                                 unsigned short* __restrict__ y,
                                 const int* __restrict__ offsets, const int* __restrict__ counts,
                                 const int* __restrict__ perm) {
    int wid = (int)((blockIdx.x * blockDim.x + threadIdx.x) >> 6);
    if (wid >= N_NODES) return;
    int lane = threadIdx.x & 63;
    int q = lane >> 4, sub = lane & 15;
    float acc[8];
#pragma unroll
    for (int i = 0; i < 8; i++) acc[i] = 0.f;
    int off = offsets[wid], cnt = counts[wid];
    for (int base = 0; base < cnt; base += 64) {
        int rem = cnt - base;
        if (rem > 64) rem = 64;
        int pl = perm[off + base + (lane < rem ? lane : 0)];
        for (int e = 0; e < rem; e += 16) {
            int id0 = __shfl(pl, e + q);
            int id1 = __shfl(pl, e + q + 4);
            int id2 = __shfl(pl, e + q + 8);
            int id3 = __shfl(pl, e + q + 12);
            uint4 v0 = *(const uint4*)(h + (size_t)id0 * 128 + sub * 8);
            uint4 v1 = *(const uint4*)(h + (size_t)id1 * 128 + sub * 8);
            uint4 v2 = *(const uint4*)(h + (size_t)id2 * 128 + sub * 8);
            uint4 v3 = *(const uint4*)(h + (size_t)id3 * 128 + sub * 8);
            uint4 z = make_uint4(0, 0, 0, 0);
            if (e + q >= rem) v0 = z;
            if (e + q + 4 >= rem) v1 = z;
            if (e + q + 8 >= rem) v2 = z;
            if (e + q + 12 >= rem) v3 = z;
            acc[0] += bflo(v0.x) + bflo(v1.x) + bflo(v2.x) + bflo(v3.x);
            acc[1] += bfhi(v0.x) + bfhi(v1.x) + bfhi(v2.x) + bfhi(v3.x);
            acc[2] += bflo(v0.y) + bflo(v1.y) + bflo(v2.y) + bflo(v3.y);
            acc[3] += bfhi(v0.y) + bfhi(v1.y) + bfhi(v2.y) + bfhi(v3.y);
            acc[4] += bflo(v0.z) + bflo(v1.z) + bflo(v2.z) + bflo(v3.z);
            acc[5] += bfhi(v0.z) + bfhi(v1.z) + bfhi(v2.z) + bfhi(v3.z);
            acc[6] += bflo(v0.w) + bflo(v1.w) + bflo(v2.w) + bflo(v3.w);
            acc[7] += bfhi(v0.w) + bfhi(v1.w) + bfhi(v2.w) + bfhi(v3.w);
        }
    }
#pragma unroll
    for (int i = 0; i < 8; i++) {
        acc[i] += __shfl_xor(acc[i], 16);
        acc[i] += __shfl_xor(acc[i], 32);
    }
    if (q == 0) {
        const uint4 sv = *(const uint4*)(h + (size_t)wid * 128 + sub * 8);
        acc[0] += bflo(sv.x); acc[1] += bfhi(sv.x);
        acc[2] += bflo(sv.y); acc[3] += bfhi(sv.y);
        acc[4] += bflo(sv.z); acc[5] += bfhi(sv.z);
        acc[6] += bflo(sv.w); acc[7] += bfhi(sv.w);
        uint4 o;
        o.x = pack2(acc[0], acc[1]);
        o.y = pack2(acc[2], acc[3]);
        o.z = pack2(acc[4], acc[5]);
        o.w = pack2(acc[6], acc[7]);
        *(uint4*)(y + (size_t)wid * 128 + sub * 8) = o;
    }
}

// ---------------- weight prep: Wt[g][n][k] bf16 (transposed, BN-scale folded) ----------
struct WArgs {
    const float *w, *b, *g, *be, *m, *v;
    int K, hasBN;
};
struct WArgs6 { WArgs a[6]; };

__global__ void prep_w_kernel(WArgs6 args, unsigned short* __restrict__ Wt,
                              float* __restrict__ shift) {
    int gi = blockIdx.x >> 3;
    int part = blockIdx.x & 7;
    WArgs A = args.a[gi];
    int t = threadIdx.x;
    int task = part * 256 + t;           // 0..2047
    int n = task & 127, kc = task >> 7;  // kc 0..15 (8-elem k-chunks)
    float scl, sft;
    if (A.hasBN) {
        float rs = rsqrtf(A.v[n] + BN_EPS);
        scl = A.g[n] * rs;
        sft = A.be[n] + (A.b[n] - A.m[n]) * scl;
    } else {
        scl = 1.f;
        sft = A.b[n];
    }
    u32 o[4];
#pragma unroll
    for (int j = 0; j < 4; j++) {
        int k0 = kc * 8 + j * 2;
        float f0 = (k0 < A.K) ? A.w[k0 * 128 + n] * scl : 0.f;
        float f1 = (k0 + 1 < A.K) ? A.w[(k0 + 1) * 128 + n] * scl : 0.f;
        o[j] = pack2(f0, f1);
    }
    *(uint4*)(Wt + (size_t)gi * 16384 + n * 128 + kc * 8) = make_uint4(o[0], o[1], o[2], o[3]);
    if (kc == 0) shift[gi * 128 + n] = sft;
}

// ---------------- fused conv MLP: Out = relu(relu(BN(In@W1))@W2), optional pool -------
// 512 threads = 8 waves x 32 rows; both GEMMs operand-swapped: mfma(W_frag, In_frag)
// -> lane's D holds one row (lane&15) with 4-col runs -> h staged to LDS via ds_write_b64.
// Zero __syncthreads: each wave owns its 32 rows end-to-end; W read from L1/L2.
template <int POOL>
__global__ __launch_bounds__(512) void conv_kernel(
    const unsigned short* __restrict__ In, const unsigned short* __restrict__ W1,
    const float* __restrict__ shift1, const unsigned short* __restrict__ W2,
    const float* __restrict__ shift2, unsigned short* __restrict__ Out,
    const int* __restrict__ batch, float* __restrict__ hg) {
    __shared__ unsigned short Hs[256 * 128];  // 64 KB swizzled h tile
    int t = threadIdx.x;
    int wave = t >> 6, lane = t & 63;
    int rowbase = blockIdx.x * 256 + wave * 32;
    int ln = lane & 15, aq = lane >> 4;
    int crow4 = aq * 4;
    f32x4 acc[2][8];
#pragma unroll
    for (int i = 0; i < 2; i++)
#pragma unroll
        for (int c = 0; c < 8; c++) acc[i][c] = (f32x4){0.f, 0.f, 0.f, 0.f};

    // ---- GEMM1': In rows as B-frags (col=row m), W1 as A-frags (row=col n) ----
    int r0 = rowbase + ln; if (r0 > N_NODES - 1) r0 = N_NODES - 1;
    int r1 = rowbase + 16 + ln; if (r1 > N_NODES - 1) r1 = N_NODES - 1;
    const unsigned short* bp0 = In + (size_t)r0 * 128 + aq * 8;
    const unsigned short* bp1 = In + (size_t)r1 * 128 + aq * 8;
#pragma unroll
    for (int s = 0; s < 4; ++s) {
        short8 b0 = *(const short8*)(bp0 + s * 32);
        short8 b1 = *(const short8*)(bp1 + s * 32);
#pragma unroll
        for (int c = 0; c < 8; ++c) {
            short8 a = *(const short8*)(W1 + (c * 16 + ln) * 128 + s * 32 + aq * 8);
            acc[0][c] = __builtin_amdgcn_mfma_f32_16x16x32_bf16(a, b0, acc[0][c], 0, 0, 0);
            acc[1][c] = __builtin_amdgcn_mfma_f32_16x16x32_bf16(a, b1, acc[1][c], 0, 0, 0);
        }
    }
    // ---- epilogue 1: h = relu(acc + shift1) -> Hs (XOR-swizzled 16B chunks) ----
    int mloc0 = wave * 32 + ln;
#pragma unroll
    for (int rt = 0; rt < 2; ++rt) {
        int m = mloc0 + rt * 16;
#pragma unroll
        for (int c = 0; c < 8; ++c) {
            int n0 = c * 16 + crow4;
            float4 sh = *(const float4*)(shift1 + n0);
            float v0 = fmaxf(acc[rt][c][0] + sh.x, 0.f);
            float v1 = fmaxf(acc[rt][c][1] + sh.y, 0.f);
            float v2 = fmaxf(acc[rt][c][2] + sh.z, 0.f);
            float v3 = fmaxf(acc[rt][c][3] + sh.w, 0.f);
            int cc = n0 >> 3;
            int addr = m * 128 + ((cc ^ (m & 7)) << 3) + (n0 & 7);
            *(uint2*)&Hs[addr] = make_uint2(pack2(v0, v1), pack2(v2, v3));
        }
    }
    // ---- GEMM2': h rows as B-frags from LDS, W2 as A-frags ----
#pragma unroll
    for (int i = 0; i < 2; i++)
#pragma unroll
        for (int c = 0; c < 8; c++) acc[i][c] = (f32x4){0.f, 0.f, 0.f, 0.f};
#pragma unroll
    for (int s = 0; s < 4; ++s) {
        int m0 = mloc0, m1 = mloc0 + 16;
        short8 b0 = *(const short8*)&Hs[m0 * 128 + (((s * 4 + aq) ^ (m0 & 7)) << 3)];
        short8 b1 = *(const short8*)&Hs[m1 * 128 + (((s * 4 + aq) ^ (m1 & 7)) << 3)];
#pragma unroll
        for (int c = 0; c < 8; ++c) {
            short8 a = *(const short8*)(W2 + (c * 16 + ln) * 128 + s * 32 + aq * 8);
            acc[0][c] = __builtin_amdgcn_mfma_f32_16x16x32_bf16(a, b0, acc[0][c], 0, 0, 0);
            acc[1][c] = __builtin_amdgcn_mfma_f32_16x16x32_bf16(a, b1, acc[1][c], 0, 0, 0);
        }
    }
    // ---- epilogue 2: relu(acc + shift2) -> Out rows (8B runs) or pool atomics ----
#pragma unroll
    for (int rt = 0; rt < 2; ++rt) {
        int row = rowbase + rt * 16 + ln;
        if (row >= N_NODES) continue;
        if (POOL) {
            float* hgp = hg + (size_t)batch[row] * 128;
#pragma unroll
            for (int c = 0; c < 8; ++c) {
                int n0 = c * 16 + crow4;
                float4 sh = *(const float4*)(shift2 + n0);
                atomicAdd(hgp + n0 + 0, fmaxf(acc[rt][c][0] + sh.x, 0.f));
                atomicAdd(hgp + n0 + 1, fmaxf(acc[rt][c][1] + sh.y, 0.f));
                atomicAdd(hgp + n0 + 2, fmaxf(acc[rt][c][2] + sh.z, 0.f));
                atomicAdd(hgp + n0 + 3, fmaxf(acc[rt][c][3] + sh.w, 0.f));
            }
        } else {
            unsigned short* op = Out + (size_t)row * 128;
#pragma unroll
            for (int c = 0; c < 8; ++c) {
                int n0 = c * 16 + crow4;
                float4 sh = *(const float4*)(shift2 + n0);
                float v0 = fmaxf(acc[rt][c][0] + sh.x, 0.f);
                float v1 = fmaxf(acc[rt][c][1] + sh.y, 0.f);
                float v2 = fmaxf(acc[rt][c][2] + sh.z, 0.f);
                float v3 = fmaxf(acc[rt][c][3] + sh.w, 0.f);
                *(uint2*)(op + n0) = make_uint2(pack2(v0, v1), pack2(v2, v3));
            }
        }
    }
}

// ---------------- head ----------------
__global__ void head_kernel(const float* __restrict__ hg, const float* __restrict__ l1w,
                            const float* __restrict__ l1b, const float* __restrict__ l2w,
                            const float* __restrict__ l2b, float* __restrict__ out) {
    __shared__ float row[128];
    int g = blockIdx.x, t = threadIdx.x;  // 64 threads
    *(float2*)&row[t * 2] = *(const float2*)&hg[g * 128 + t * 2];
    __syncthreads();
    float a = l1b[t];
    for (int k = 0; k < 128; k++) a = fmaf(row[k], l1w[k * 64 + t], a);
    a = fmaxf(a, 0.f);
    float p = a * l2w[t];
    for (int d = 32; d; d >>= 1) p += __shfl_down(p, d);
    if (t == 0) out[g] = 1.f / (1.f + expf(-(p + l2b[0])));
}

extern "C" void kernel_launch(void* const* d_in, const int* in_sizes, int n_in,
                              void* d_out, int out_size, void* d_ws, size_t ws_size,
                              hipStream_t stream) {
    (void)in_sizes; (void)n_in; (void)out_size; (void)ws_size;
    const float* x = (const float*)d_in[0];
    const int* ei = (const int*)d_in[1];
    const int* batch = (const int*)d_in[2];
    WArgs6 wa;
    for (int i = 0; i < 3; i++) {
        int base = 3 + i * 8;
        wa.a[i * 2] = WArgs{(const float*)d_in[base + 0], (const float*)d_in[base + 1],
                            (const float*)d_in[base + 2], (const float*)d_in[base + 3],
                            (const float*)d_in[base + 4], (const float*)d_in[base + 5],
                            (i == 0) ? IN_DIM : DIM_H, 1};
        wa.a[i * 2 + 1] = WArgs{(const float*)d_in[base + 6], (const float*)d_in[base + 7],
                                nullptr, nullptr, nullptr, nullptr, DIM_H, 0};
    }
    const float* l1w = (const float*)d_in[27];
    const float* l1b = (const float*)d_in[28];
    const float* l2w = (const float*)d_in[29];
    const float* l2b = (const float*)d_in[30];

    char* ws = (char*)d_ws;
    size_t off = 0;
    auto alloc = [&](size_t bytes) -> void* {
        void* p = ws + off;
        off += (bytes + 511) & ~(size_t)511;
        return p;
    };
    unsigned short* A = (unsigned short*)alloc((size_t)N_NODES * 128 * 2);
    unsigned short* B = (unsigned short*)alloc((size_t)N_NODES * 128 * 2);
    float* hg = (float*)alloc((size_t)N_GRAPHS * 128 * 4);
    unsigned short* Wt = (unsigned short*)alloc((size_t)6 * 16384 * 2);
    float* shift = (float*)alloc(6 * 128 * 4);
    int* counts = (int*)alloc((size_t)N_NODES * 4);
    int* offsets = (int*)alloc((size_t)N_NODES * 4);
    int* perm = (int*)alloc((size_t)N_EDGES * 4);
    uint2* ebuf = (uint2*)alloc((size_t)N_EDGES * 8);
    int* bucket_count = (int*)alloc((NBUCK + 1) * 4);
    int* bucket_base = (int*)alloc((NBUCK + 1) * 4);
    int* bucket_cursor = (int*)alloc(NBUCK * 4);

    const int* src = ei;
    const int* dst = ei + N_EDGES;

    hipMemsetAsync(bucket_count, 0, (NBUCK + 1) * 4, stream);
    hipMemsetAsync(hg, 0, (size_t)N_GRAPHS * 128 * 4, stream);
    bucket_count_kernel<<<256, 256, 0, stream>>>(dst, bucket_count);
    bucket_scan_kernel<<<1, 128, 0, stream>>>(bucket_count, bucket_base, bucket_cursor);
    bucket_scatter_kernel<<<256, 256, 0, stream>>>(src, dst, bucket_cursor, ebuf);
    bucket_build_kernel<<<NBUCK, 512, 0, stream>>>(ebuf, bucket_base, counts, offsets, perm);
    prep_w_kernel<<<48, 256, 0, stream>>>(wa, Wt, shift);
    pad_x_kernel<<<(N_NODES * 64 + 255) / 256, 256, 0, stream>>>(x, A);

    const int CB = (N_NODES + 255) / 256;  // 196
    for (int l = 0; l < 3; ++l) {
        aggregate_kernel<<<(N_NODES * 64 + 255) / 256, 256, 0, stream>>>(A, B, offsets, counts, perm);
        const unsigned short* W1 = Wt + (size_t)(l * 2) * 16384;
        const unsigned short* W2 = Wt + (size_t)(l * 2 + 1) * 16384;
        const float* s1 = shift + (l * 2) * 128;
        const float* s2 = shift + (l * 2 + 1) * 128;
        if (l < 2)
            conv_kernel<0><<<CB, 512, 0, stream>>>(B, W1, s1, W2, s2, A, batch, hg);
        else
            conv_kernel<1><<<CB, 512, 0, stream>>>(B, W1, s1, W2, s2, A, batch, hg);
    }
    head_kernel<<<N_GRAPHS, 64, 0, stream>>>(hg, l1w, l1b, l2w, l2b, (float*)d_out);
}

// Round 4
// 371.542 us; speedup vs baseline: 2.1475x; 2.1475x over previous
//
#include <hip/hip_runtime.h>
#include <math.h>

#define N_NODES 50000
#define N_EDGES 800000
#define N_GRAPHS 512
#define IN_DIM 126
#define DIM_H 128
#define BN_EPS 1e-5f
#define NBUCK 98  // dst >> 9 -> 98 buckets of 512 nodes

typedef unsigned int u32;
typedef short short8 __attribute__((ext_vector_type(8)));
typedef float f32x4 __attribute__((ext_vector_type(4)));

__device__ __forceinline__ unsigned short f2bf(float f) {
    u32 u = __float_as_uint(f);
    u += 0x7fffu + ((u >> 16) & 1u);  // RNE
    return (unsigned short)(u >> 16);
}
__device__ __forceinline__ float bflo(u32 u) { return __uint_as_float(u << 16); }
__device__ __forceinline__ float bfhi(u32 u) { return __uint_as_float(u & 0xffff0000u); }
__device__ __forceinline__ u32 pack2(float a, float b) {
    return (u32)f2bf(a) | ((u32)f2bf(b) << 16);
}

// ---------------- pad x [50000,126] fp32 -> A [50000,128] bf16 ----------------
__global__ void pad_x_kernel(const float* __restrict__ x, unsigned short* __restrict__ A) {
    int tid = blockIdx.x * blockDim.x + threadIdx.x;
    int n = tid >> 6, c2 = tid & 63;
    if (n >= N_NODES) return;
    int c = c2 * 2;
    float f0 = (c < IN_DIM) ? x[n * IN_DIM + c] : 0.f;
    float f1 = (c + 1 < IN_DIM) ? x[n * IN_DIM + c + 1] : 0.f;
    ((u32*)A)[tid] = pack2(f0, f1);
}

// ---------------- bucketed CSR build (XCD-local perm writes) ----------------
__global__ void bucket_count_kernel(const int* __restrict__ dst, int* __restrict__ bucket_count) {
    __shared__ int hist[NBUCK];
    int b = blockIdx.x, t = threadIdx.x;
    if (t < NBUCK) hist[t] = 0;
    __syncthreads();
    int e0 = b * 3125;
    for (int i = t; i < 3125; i += 256) atomicAdd(&hist[dst[e0 + i] >> 9], 1);
    __syncthreads();
    if (t < NBUCK && hist[t]) atomicAdd(&bucket_count[t], hist[t]);
}

__global__ void bucket_scan_kernel(const int* __restrict__ bucket_count,
                                   int* __restrict__ bucket_base, int* __restrict__ bucket_cursor) {
    __shared__ int s[128];
    int t = threadIdx.x;
    int v = (t < NBUCK) ? bucket_count[t] : 0;
    s[t] = v;
    __syncthreads();
    for (int d = 1; d < 128; d <<= 1) {
        int add = (t >= d) ? s[t - d] : 0;
        __syncthreads();
        s[t] += add;
        __syncthreads();
    }
    if (t < NBUCK) {
        int excl = s[t] - v;
        bucket_base[t] = excl;
        bucket_cursor[t] = excl;
        if (t == NBUCK - 1) bucket_base[NBUCK] = s[t];
    }
}

__global__ void bucket_scatter_kernel(const int* __restrict__ src, const int* __restrict__ dst,
                                      int* __restrict__ bucket_cursor, uint2* __restrict__ ebuf) {
    __shared__ int hist[NBUCK], base[NBUCK];
    int b = blockIdx.x, t = threadIdx.x;
    if (t < NBUCK) hist[t] = 0;
    __syncthreads();
    int e0 = b * 3125;
    for (int i = t; i < 3125; i += 256) atomicAdd(&hist[dst[e0 + i] >> 9], 1);
    __syncthreads();
    if (t < NBUCK && hist[t]) base[t] = atomicAdd(&bucket_cursor[t], hist[t]);
    __syncthreads();
    if (t < NBUCK) hist[t] = 0;  // reuse as running cursor
    __syncthreads();
    for (int i = t; i < 3125; i += 256) {
        int s = src[e0 + i], d = dst[e0 + i];
        int k = d >> 9;
        int p = base[k] + atomicAdd(&hist[k], 1);
        ebuf[p] = make_uint2((u32)s, (u32)d);
    }
}

__global__ __launch_bounds__(512) void bucket_build_kernel(
    const uint2* __restrict__ ebuf, const int* __restrict__ bucket_base,
    int* __restrict__ counts, int* __restrict__ offsets, int* __restrict__ perm) {
    __shared__ int hist[512], ex[512];
    int k = blockIdx.x, t = threadIdx.x;
    int nb = k << 9;
    int bb = bucket_base[k], bcnt = bucket_base[k + 1] - bb;
    hist[t] = 0;
    __syncthreads();
    for (int e = t; e < bcnt; e += 512) atomicAdd(&hist[(int)ebuf[bb + e].y - nb], 1);
    __syncthreads();
    int v = hist[t];
    ex[t] = v;
    __syncthreads();
    for (int d = 1; d < 512; d <<= 1) {
        int add = (t >= d) ? ex[t - d] : 0;
        __syncthreads();
        ex[t] += add;
        __syncthreads();
    }
    int excl = ex[t] - v;  // exclusive scan
    int node = nb + t;
    if (node < N_NODES) {
        counts[node] = v;
        offsets[node] = bb + excl;
    }
    __syncthreads();
    hist[t] = excl;  // reuse as running cursor (bucket-relative)
    __syncthreads();
    for (int e = t; e < bcnt; e += 512) {
        uint2 ed = ebuf[bb + e];
        int p = atomicAdd(&hist[(int)ed.y - nb], 1);
        perm[bb + p] = (int)ed.x;
    }
}

// ---------------- aggregate: y[n] = h[n] + sum_{e: dst=n} h[src(e)]  (bf16 rows) ----------
__global__ void aggregate_kernel(const unsigned short* __restrict__ h,
                                 unsigned short* __restrict__ y,
                                 const int* __restrict__ offsets, const int* __restrict__ counts,
                                 const int* __restrict__ perm) {
    int wid = (int)((blockIdx.x * blockDim.x + threadIdx.x) >> 6);
    if (wid >= N_NODES) return;
    int lane = threadIdx.x & 63;
    int q = lane >> 4, sub = lane & 15;
    float acc[8];
#pragma unroll
    for (int i = 0; i < 8; i++) acc[i] = 0.f;
    int off = offsets[wid], cnt = counts[wid];
    for (int base = 0; base < cnt; base += 64) {
        int rem = cnt - base;
        if (rem > 64) rem = 64;
        int pl = perm[off + base + (lane < rem ? lane : 0)];
        for (int e = 0; e < rem; e += 16) {
            int id0 = __shfl(pl, e + q);
            int id1 = __shfl(pl, e + q + 4);
            int id2 = __shfl(pl, e + q + 8);
            int id3 = __shfl(pl, e + q + 12);
            uint4 v0 = *(const uint4*)(h + (size_t)id0 * 128 + sub * 8);
            uint4 v1 = *(const uint4*)(h + (size_t)id1 * 128 + sub * 8);
            uint4 v2 = *(const uint4*)(h + (size_t)id2 * 128 + sub * 8);
            uint4 v3 = *(const uint4*)(h + (size_t)id3 * 128 + sub * 8);
            uint4 z = make_uint4(0, 0, 0, 0);
            if (e + q >= rem) v0 = z;
            if (e + q + 4 >= rem) v1 = z;
            if (e + q + 8 >= rem) v2 = z;
            if (e + q + 12 >= rem) v3 = z;
            acc[0] += bflo(v0.x) + bflo(v1.x) + bflo(v2.x) + bflo(v3.x);
            acc[1] += bfhi(v0.x) + bfhi(v1.x) + bfhi(v2.x) + bfhi(v3.x);
            acc[2] += bflo(v0.y) + bflo(v1.y) + bflo(v2.y) + bflo(v3.y);
            acc[3] += bfhi(v0.y) + bfhi(v1.y) + bfhi(v2.y) + bfhi(v3.y);
            acc[4] += bflo(v0.z) + bflo(v1.z) + bflo(v2.z) + bflo(v3.z);
            acc[5] += bfhi(v0.z) + bfhi(v1.z) + bfhi(v2.z) + bfhi(v3.z);
            acc[6] += bflo(v0.w) + bflo(v1.w) + bflo(v2.w) + bflo(v3.w);
            acc[7] += bfhi(v0.w) + bfhi(v1.w) + bfhi(v2.w) + bfhi(v3.w);
        }
    }
#pragma unroll
    for (int i = 0; i < 8; i++) {
        acc[i] += __shfl_xor(acc[i], 16);
        acc[i] += __shfl_xor(acc[i], 32);
    }
    if (q == 0) {
        const uint4 sv = *(const uint4*)(h + (size_t)wid * 128 + sub * 8);
        acc[0] += bflo(sv.x); acc[1] += bfhi(sv.x);
        acc[2] += bflo(sv.y); acc[3] += bfhi(sv.y);
        acc[4] += bflo(sv.z); acc[5] += bfhi(sv.z);
        acc[6] += bflo(sv.w); acc[7] += bfhi(sv.w);
        uint4 o;
        o.x = pack2(acc[0], acc[1]);
        o.y = pack2(acc[2], acc[3]);
        o.z = pack2(acc[4], acc[5]);
        o.w = pack2(acc[6], acc[7]);
        *(uint4*)(y + (size_t)wid * 128 + sub * 8) = o;
    }
}

// ---------------- weight prep: Wt[g][n][k] bf16, BN-folded, chunk-XOR swizzled ----------
struct WArgs {
    const float *w, *b, *g, *be, *m, *v;
    int K, hasBN;
};
struct WArgs6 { WArgs a[6]; };

__global__ void prep_w_kernel(WArgs6 args, unsigned short* __restrict__ Wt,
                              float* __restrict__ shift) {
    int gi = blockIdx.x >> 3;
    int part = blockIdx.x & 7;
    WArgs A = args.a[gi];
    int t = threadIdx.x;
    int task = part * 256 + t;           // 0..2047
    int n = task & 127, kc = task >> 7;  // kc 0..15 (8-elem k-chunks)
    float scl, sft;
    if (A.hasBN) {
        float rs = rsqrtf(A.v[n] + BN_EPS);
        scl = A.g[n] * rs;
        sft = A.be[n] + (A.b[n] - A.m[n]) * scl;
    } else {
        scl = 1.f;
        sft = A.b[n];
    }
    u32 o[4];
#pragma unroll
    for (int j = 0; j < 4; j++) {
        int k0 = kc * 8 + j * 2;
        float f0 = (k0 < A.K) ? A.w[k0 * 128 + n] * scl : 0.f;
        float f1 = (k0 + 1 < A.K) ? A.w[(k0 + 1) * 128 + n] * scl : 0.f;
        o[j] = pack2(f0, f1);
    }
    unsigned short* dst = Wt + (size_t)gi * 16384 + n * 128 + ((kc ^ (n & 7)) * 8);
    *(uint4*)dst = make_uint4(o[0], o[1], o[2], o[3]);
    if (kc == 0) shift[gi * 128 + n] = sft;
}

// ---------------- GEMM: Out = relu(A @ W' + shift), bf16 in/out, MFMA ----------------
// block: 256 threads (4 waves), 128 rows; wave w -> rows [w*32, w*32+32)  [R2-proven]
__global__ __launch_bounds__(256) void gemm_mfma_kernel(
    const unsigned short* __restrict__ A, const unsigned short* __restrict__ Wt,
    const float* __restrict__ shift, unsigned short* __restrict__ Out) {
    __shared__ unsigned short Ws[128 * 128];  // 32 KB, swizzled chunks
    __shared__ float sh[128];
    int t = threadIdx.x;
    {
        const float4* src = (const float4*)Wt;
        float4* dst = (float4*)Ws;
#pragma unroll
        for (int i = 0; i < 8; i++) dst[t + i * 256] = src[t + i * 256];
        if (t < 128) sh[t] = shift[t];
    }
    __syncthreads();
    int wave = t >> 6, lane = t & 63;
    int row0 = blockIdx.x * 128 + wave * 32;
    int arow = lane & 15, aq = lane >> 4;  // fragment: row=lane&15, kchunk=lane>>4
    int r0i = row0 + arow; if (r0i > N_NODES - 1) r0i = N_NODES - 1;
    int r1i = row0 + 16 + arow; if (r1i > N_NODES - 1) r1i = N_NODES - 1;
    const unsigned short* a0p = A + (size_t)r0i * 128 + aq * 8;
    const unsigned short* a1p = A + (size_t)r1i * 128 + aq * 8;
    f32x4 acc[2][8];
#pragma unroll
    for (int i = 0; i < 2; i++)
#pragma unroll
        for (int c = 0; c < 8; c++) acc[i][c] = (f32x4){0.f, 0.f, 0.f, 0.f};

#pragma unroll
    for (int s = 0; s < 4; s++) {
        short8 a0 = *(const short8*)(a0p + s * 32);
        short8 a1 = *(const short8*)(a1p + s * 32);
#pragma unroll
        for (int c = 0; c < 8; c++) {
            int n = c * 16 + arow;                  // B col
            int kc = (s * 4 + aq) ^ (n & 7);        // swizzled k-chunk
            short8 b = *(const short8*)&Ws[n * 128 + kc * 8];
            acc[0][c] = __builtin_amdgcn_mfma_f32_16x16x32_bf16(a0, b, acc[0][c], 0, 0, 0);
            acc[1][c] = __builtin_amdgcn_mfma_f32_16x16x32_bf16(a1, b, acc[1][c], 0, 0, 0);
        }
    }
    // C/D layout: col = lane&15, row = (lane>>4)*4 + j
    int ccol = lane & 15, crow4 = (lane >> 4) * 4;
#pragma unroll
    for (int rt = 0; rt < 2; rt++) {
#pragma unroll
        for (int c = 0; c < 8; c++) {
            float s0 = sh[c * 16 + ccol];
#pragma unroll
            for (int j = 0; j < 4; j++) {
                int grow = row0 + rt * 16 + crow4 + j;
                if (grow < N_NODES) {
                    float v = fmaxf(acc[rt][c][j] + s0, 0.f);
                    Out[(size_t)grow * 128 + c * 16 + ccol] = f2bf(v);
                }
            }
        }
    }
}

// ---------------- global add pool (bf16 h -> fp32 hg) ----------------
__global__ void pool_kernel(const unsigned short* __restrict__ h, const int* __restrict__ batch,
                            float* __restrict__ hg) {
    int tid = blockIdx.x * blockDim.x + threadIdx.x;
    int n = tid >> 6, l = tid & 63;
    if (n >= N_NODES) return;
    int g = batch[n];
    u32 v = ((const u32*)h)[n * 64 + l];
    atomicAdd(&hg[g * 128 + l * 2], bflo(v));
    atomicAdd(&hg[g * 128 + l * 2 + 1], bfhi(v));
}

// ---------------- head ----------------
__global__ void head_kernel(const float* __restrict__ hg, const float* __restrict__ l1w,
                            const float* __restrict__ l1b, const float* __restrict__ l2w,
                            const float* __restrict__ l2b, float* __restrict__ out) {
    __shared__ float row[128];
    int g = blockIdx.x, t = threadIdx.x;  // 64 threads
    *(float2*)&row[t * 2] = *(const float2*)&hg[g * 128 + t * 2];
    __syncthreads();
    float a = l1b[t];
    for (int k = 0; k < 128; k++) a = fmaf(row[k], l1w[k * 64 + t], a);
    a = fmaxf(a, 0.f);
    float p = a * l2w[t];
    for (int d = 32; d; d >>= 1) p += __shfl_down(p, d);
    if (t == 0) out[g] = 1.f / (1.f + expf(-(p + l2b[0])));
}

extern "C" void kernel_launch(void* const* d_in, const int* in_sizes, int n_in,
                              void* d_out, int out_size, void* d_ws, size_t ws_size,
                              hipStream_t stream) {
    (void)in_sizes; (void)n_in; (void)out_size; (void)ws_size;
    const float* x = (const float*)d_in[0];
    const int* ei = (const int*)d_in[1];
    const int* batch = (const int*)d_in[2];
    WArgs6 wa;
    for (int i = 0; i < 3; i++) {
        int base = 3 + i * 8;
        wa.a[i * 2] = WArgs{(const float*)d_in[base + 0], (const float*)d_in[base + 1],
                            (const float*)d_in[base + 2], (const float*)d_in[base + 3],
                            (const float*)d_in[base + 4], (const float*)d_in[base + 5],
                            (i == 0) ? IN_DIM : DIM_H, 1};
        wa.a[i * 2 + 1] = WArgs{(const float*)d_in[base + 6], (const float*)d_in[base + 7],
                                nullptr, nullptr, nullptr, nullptr, DIM_H, 0};
    }
    const float* l1w = (const float*)d_in[27];
    const float* l1b = (const float*)d_in[28];
    const float* l2w = (const float*)d_in[29];
    const float* l2b = (const float*)d_in[30];

    char* ws = (char*)d_ws;
    size_t off = 0;
    auto alloc = [&](size_t bytes) -> void* {
        void* p = ws + off;
        off += (bytes + 511) & ~(size_t)511;
        return p;
    };
    unsigned short* A = (unsigned short*)alloc((size_t)N_NODES * 128 * 2);
    unsigned short* B = (unsigned short*)alloc((size_t)N_NODES * 128 * 2);
    unsigned short* C = (unsigned short*)alloc((size_t)N_NODES * 128 * 2);
    float* hg = (float*)alloc((size_t)N_GRAPHS * 128 * 4);
    unsigned short* Wt = (unsigned short*)alloc((size_t)6 * 16384 * 2);
    float* shift = (float*)alloc(6 * 128 * 4);
    int* counts = (int*)alloc((size_t)N_NODES * 4);
    int* offsets = (int*)alloc((size_t)N_NODES * 4);
    int* perm = (int*)alloc((size_t)N_EDGES * 4);
    uint2* ebuf = (uint2*)alloc((size_t)N_EDGES * 8);
    int* bucket_count = (int*)alloc((NBUCK + 1) * 4);
    int* bucket_base = (int*)alloc((NBUCK + 1) * 4);
    int* bucket_cursor = (int*)alloc(NBUCK * 4);

    const int* src = ei;
    const int* dst = ei + N_EDGES;

    hipMemsetAsync(bucket_count, 0, (NBUCK + 1) * 4, stream);
    hipMemsetAsync(hg, 0, (size_t)N_GRAPHS * 128 * 4, stream);
    bucket_count_kernel<<<256, 256, 0, stream>>>(dst, bucket_count);
    bucket_scan_kernel<<<1, 128, 0, stream>>>(bucket_count, bucket_base, bucket_cursor);
    bucket_scatter_kernel<<<256, 256, 0, stream>>>(src, dst, bucket_cursor, ebuf);
    bucket_build_kernel<<<NBUCK, 512, 0, stream>>>(ebuf, bucket_base, counts, offsets, perm);
    prep_w_kernel<<<48, 256, 0, stream>>>(wa, Wt, shift);
    pad_x_kernel<<<(N_NODES * 64 + 255) / 256, 256, 0, stream>>>(x, A);

    const int GB = (N_NODES + 127) / 128;  // 391
    for (int l = 0; l < 3; ++l) {
        aggregate_kernel<<<(N_NODES * 64 + 255) / 256, 256, 0, stream>>>(A, B, offsets, counts, perm);
        gemm_mfma_kernel<<<GB, 256, 0, stream>>>(B, Wt + (size_t)(l * 2) * 16384,
                                                 shift + (l * 2) * 128, C);
        gemm_mfma_kernel<<<GB, 256, 0, stream>>>(C, Wt + (size_t)(l * 2 + 1) * 16384,
                                                 shift + (l * 2 + 1) * 128, A);
    }
    pool_kernel<<<(N_NODES * 64 + 255) / 256, 256, 0, stream>>>(A, batch, hg);
    head_kernel<<<N_GRAPHS, 64, 0, stream>>>(hg, l1w, l1b, l2w, l2b, (float*)d_out);
}

// Round 6
// 337.580 us; speedup vs baseline: 2.3635x; 1.1006x over previous
//
#include <hip/hip_runtime.h>
#include <math.h>

#define N_NODES 50000
#define N_EDGES 800000
#define N_GRAPHS 512
#define IN_DIM 126
#define DIM_H 128
#define BN_EPS 1e-5f
#define NBUCK 98  // dst >> 9 -> 98 buckets of 512 nodes

typedef unsigned int u32;
typedef short short8 __attribute__((ext_vector_type(8)));
typedef float f32x4 __attribute__((ext_vector_type(4)));

__device__ __forceinline__ unsigned short f2bf(float f) {
    u32 u = __float_as_uint(f);
    u += 0x7fffu + ((u >> 16) & 1u);  // RNE
    return (unsigned short)(u >> 16);
}
__device__ __forceinline__ float bflo(u32 u) { return __uint_as_float(u << 16); }
__device__ __forceinline__ float bfhi(u32 u) { return __uint_as_float(u & 0xffff0000u); }
__device__ __forceinline__ u32 pack2(float a, float b) {
    return (u32)f2bf(a) | ((u32)f2bf(b) << 16);
}

// ---------------- pad x [50000,126] fp32 -> A [50000,128] bf16 ----------------
__global__ void pad_x_kernel(const float* __restrict__ x, unsigned short* __restrict__ A) {
    int tid = blockIdx.x * blockDim.x + threadIdx.x;
    int n = tid >> 6, c2 = tid & 63;
    if (n >= N_NODES) return;
    int c = c2 * 2;
    float f0 = (c < IN_DIM) ? x[n * IN_DIM + c] : 0.f;
    float f1 = (c + 1 < IN_DIM) ? x[n * IN_DIM + c + 1] : 0.f;
    ((u32*)A)[tid] = pack2(f0, f1);
}

// ---------------- bucketed CSR build (XCD-local perm writes) ----------------
__global__ void bucket_count_kernel(const int* __restrict__ dst, int* __restrict__ bucket_count) {
    __shared__ int hist[NBUCK];
    int b = blockIdx.x, t = threadIdx.x;
    if (t < NBUCK) hist[t] = 0;
    __syncthreads();
    int e0 = b * 3125;
    for (int i = t; i < 3125; i += 256) atomicAdd(&hist[dst[e0 + i] >> 9], 1);
    __syncthreads();
    if (t < NBUCK && hist[t]) atomicAdd(&bucket_count[t], hist[t]);
}

__global__ void bucket_scan_kernel(const int* __restrict__ bucket_count,
                                   int* __restrict__ bucket_base, int* __restrict__ bucket_cursor) {
    __shared__ int s[128];
    int t = threadIdx.x;
    int v = (t < NBUCK) ? bucket_count[t] : 0;
    s[t] = v;
    __syncthreads();
    for (int d = 1; d < 128; d <<= 1) {
        int add = (t >= d) ? s[t - d] : 0;
        __syncthreads();
        s[t] += add;
        __syncthreads();
    }
    if (t < NBUCK) {
        int excl = s[t] - v;
        bucket_base[t] = excl;
        bucket_cursor[t] = excl;
        if (t == NBUCK - 1) bucket_base[NBUCK] = s[t];
    }
}

__global__ void bucket_scatter_kernel(const int* __restrict__ src, const int* __restrict__ dst,
                                      int* __restrict__ bucket_cursor, uint2* __restrict__ ebuf) {
    __shared__ int hist[NBUCK], base[NBUCK];
    int b = blockIdx.x, t = threadIdx.x;
    if (t < NBUCK) hist[t] = 0;
    __syncthreads();
    int e0 = b * 3125;
    for (int i = t; i < 3125; i += 256) atomicAdd(&hist[dst[e0 + i] >> 9], 1);
    __syncthreads();
    if (t < NBUCK && hist[t]) base[t] = atomicAdd(&bucket_cursor[t], hist[t]);
    __syncthreads();
    if (t < NBUCK) hist[t] = 0;  // reuse as running cursor
    __syncthreads();
    for (int i = t; i < 3125; i += 256) {
        int s = src[e0 + i], d = dst[e0 + i];
        int k = d >> 9;
        int p = base[k] + atomicAdd(&hist[k], 1);
        ebuf[p] = make_uint2((u32)s, (u32)d);
    }
}

__global__ __launch_bounds__(512) void bucket_build_kernel(
    const uint2* __restrict__ ebuf, const int* __restrict__ bucket_base,
    int* __restrict__ counts, int* __restrict__ offsets, int* __restrict__ perm) {
    __shared__ int hist[512], ex[512];
    int k = blockIdx.x, t = threadIdx.x;
    int nb = k << 9;
    int bb = bucket_base[k], bcnt = bucket_base[k + 1] - bb;
    hist[t] = 0;
    __syncthreads();
    for (int e = t; e < bcnt; e += 512) atomicAdd(&hist[(int)ebuf[bb + e].y - nb], 1);
    __syncthreads();
    int v = hist[t];
    ex[t] = v;
    __syncthreads();
    for (int d = 1; d < 512; d <<= 1) {
        int add = (t >= d) ? ex[t - d] : 0;
        __syncthreads();
        ex[t] += add;
        __syncthreads();
    }
    int excl = ex[t] - v;  // exclusive scan
    int node = nb + t;
    if (node < N_NODES) {
        counts[node] = v;
        offsets[node] = bb + excl;
    }
    __syncthreads();
    hist[t] = excl;  // reuse as running cursor (bucket-relative)
    __syncthreads();
    for (int e = t; e < bcnt; e += 512) {
        uint2 ed = ebuf[bb + e];
        int p = atomicAdd(&hist[(int)ed.y - nb], 1);
        perm[bb + p] = (int)ed.x;
    }
}

// ---------------- aggregate: y[n] = h[n] + sum_{e: dst=n} h[src(e)]  (bf16 rows) ----------
__global__ void aggregate_kernel(const unsigned short* __restrict__ h,
                                 unsigned short* __restrict__ y,
                                 const int* __restrict__ offsets, const int* __restrict__ counts,
                                 const int* __restrict__ perm) {
    int wid = (int)((blockIdx.x * blockDim.x + threadIdx.x) >> 6);
    if (wid >= N_NODES) return;
    int lane = threadIdx.x & 63;
    int q = lane >> 4, sub = lane & 15;
    float acc[8];
#pragma unroll
    for (int i = 0; i < 8; i++) acc[i] = 0.f;
    int off = offsets[wid], cnt = counts[wid];
    for (int base = 0; base < cnt; base += 64) {
        int rem = cnt - base;
        if (rem > 64) rem = 64;
        int pl = perm[off + base + (lane < rem ? lane : 0)];
        for (int e = 0; e < rem; e += 16) {
            int id0 = __shfl(pl, e + q);
            int id1 = __shfl(pl, e + q + 4);
            int id2 = __shfl(pl, e + q + 8);
            int id3 = __shfl(pl, e + q + 12);
            uint4 v0 = *(const uint4*)(h + (size_t)id0 * 128 + sub * 8);
            uint4 v1 = *(const uint4*)(h + (size_t)id1 * 128 + sub * 8);
            uint4 v2 = *(const uint4*)(h + (size_t)id2 * 128 + sub * 8);
            uint4 v3 = *(const uint4*)(h + (size_t)id3 * 128 + sub * 8);
            uint4 z = make_uint4(0, 0, 0, 0);
            if (e + q >= rem) v0 = z;
            if (e + q + 4 >= rem) v1 = z;
            if (e + q + 8 >= rem) v2 = z;
            if (e + q + 12 >= rem) v3 = z;
            acc[0] += bflo(v0.x) + bflo(v1.x) + bflo(v2.x) + bflo(v3.x);
            acc[1] += bfhi(v0.x) + bfhi(v1.x) + bfhi(v2.x) + bfhi(v3.x);
            acc[2] += bflo(v0.y) + bflo(v1.y) + bflo(v2.y) + bflo(v3.y);
            acc[3] += bfhi(v0.y) + bfhi(v1.y) + bfhi(v2.y) + bfhi(v3.y);
            acc[4] += bflo(v0.z) + bflo(v1.z) + bflo(v2.z) + bflo(v3.z);
            acc[5] += bfhi(v0.z) + bfhi(v1.z) + bfhi(v2.z) + bfhi(v3.z);
            acc[6] += bflo(v0.w) + bflo(v1.w) + bflo(v2.w) + bflo(v3.w);
            acc[7] += bfhi(v0.w) + bfhi(v1.w) + bfhi(v2.w) + bfhi(v3.w);
        }
    }
#pragma unroll
    for (int i = 0; i < 8; i++) {
        acc[i] += __shfl_xor(acc[i], 16);
        acc[i] += __shfl_xor(acc[i], 32);
    }
    if (q == 0) {
        const uint4 sv = *(const uint4*)(h + (size_t)wid * 128 + sub * 8);
        acc[0] += bflo(sv.x); acc[1] += bfhi(sv.x);
        acc[2] += bflo(sv.y); acc[3] += bfhi(sv.y);
        acc[4] += bflo(sv.z); acc[5] += bfhi(sv.z);
        acc[6] += bflo(sv.w); acc[7] += bfhi(sv.w);
        uint4 o;
        o.x = pack2(acc[0], acc[1]);
        o.y = pack2(acc[2], acc[3]);
        o.z = pack2(acc[4], acc[5]);
        o.w = pack2(acc[6], acc[7]);
        *(uint4*)(y + (size_t)wid * 128 + sub * 8) = o;
    }
}

// ---------------- weight prep: Wt[g][n][k] bf16, BN-folded, chunk-XOR swizzled ----------
struct WArgs {
    const float *w, *b, *g, *be, *m, *v;
    int K, hasBN;
};
struct WArgs6 { WArgs a[6]; };

__global__ void prep_w_kernel(WArgs6 args, unsigned short* __restrict__ Wt,
                              float* __restrict__ shift) {
    int gi = blockIdx.x >> 3;
    int part = blockIdx.x & 7;
    WArgs A = args.a[gi];
    int t = threadIdx.x;
    int task = part * 256 + t;           // 0..2047
    int n = task & 127, kc = task >> 7;  // kc 0..15 (8-elem k-chunks)
    float scl, sft;
    if (A.hasBN) {
        float rs = rsqrtf(A.v[n] + BN_EPS);
        scl = A.g[n] * rs;
        sft = A.be[n] + (A.b[n] - A.m[n]) * scl;
    } else {
        scl = 1.f;
        sft = A.b[n];
    }
    u32 o[4];
#pragma unroll
    for (int j = 0; j < 4; j++) {
        int k0 = kc * 8 + j * 2;
        float f0 = (k0 < A.K) ? A.w[k0 * 128 + n] * scl : 0.f;
        float f1 = (k0 + 1 < A.K) ? A.w[(k0 + 1) * 128 + n] * scl : 0.f;
        o[j] = pack2(f0, f1);
    }
    unsigned short* dst = Wt + (size_t)gi * 16384 + n * 128 + ((kc ^ (n & 7)) * 8);
    *(uint4*)dst = make_uint4(o[0], o[1], o[2], o[3]);
    if (kc == 0) shift[gi * 128 + n] = sft;
}

// ---------------- fused conv: Out = relu(relu(BN(In@W1))@W2) ----------------
// 256 threads / 4 waves / 128 rows per block. Both MFMAs operand-swapped
// (mfma(Wfrag, rowfrag)) so lane holds row-major 4-col runs -> b64 LDS/global writes.
// W1 then W2 staged into the same 32KB Ws; h tile lives in 32KB Hs. 64KB LDS = 2 blk/CU.
__global__ __launch_bounds__(256) void conv_fused_kernel(
    const unsigned short* __restrict__ In, const unsigned short* __restrict__ W1,
    const float* __restrict__ shift1, const unsigned short* __restrict__ W2,
    const float* __restrict__ shift2, unsigned short* __restrict__ Out) {
    __shared__ unsigned short Ws[128 * 128];  // 32 KB (swizzled chunks)
    __shared__ unsigned short Hs[128 * 128];  // 32 KB (swizzled chunks)
    int t = threadIdx.x;
    // stage W1
    {
        const float4* srcp = (const float4*)W1;
        float4* dstp = (float4*)Ws;
#pragma unroll
        for (int i = 0; i < 8; i++) dstp[t + i * 256] = srcp[t + i * 256];
    }
    __syncthreads();

    int wave = t >> 6, lane = t & 63;
    int rowbase = blockIdx.x * 128 + wave * 32;
    int ln = lane & 15, aq = lane >> 4;
    int crow4 = aq * 4;
    f32x4 acc[2][8];
#pragma unroll
    for (int i = 0; i < 2; i++)
#pragma unroll
        for (int c = 0; c < 8; c++) acc[i][c] = (f32x4){0.f, 0.f, 0.f, 0.f};

    // ---- GEMM1 (swapped): B-frags = In rows from global, A-frags = W1 from LDS ----
    int r0 = rowbase + ln; if (r0 > N_NODES - 1) r0 = N_NODES - 1;
    int r1 = rowbase + 16 + ln; if (r1 > N_NODES - 1) r1 = N_NODES - 1;
    const unsigned short* bp0 = In + (size_t)r0 * 128 + aq * 8;
    const unsigned short* bp1 = In + (size_t)r1 * 128 + aq * 8;
#pragma unroll
    for (int s = 0; s < 4; ++s) {
        short8 b0 = *(const short8*)(bp0 + s * 32);
        short8 b1 = *(const short8*)(bp1 + s * 32);
#pragma unroll
        for (int c = 0; c < 8; ++c) {
            int n = c * 16 + ln;
            short8 wf = *(const short8*)&Ws[n * 128 + (((s * 4 + aq) ^ (n & 7)) << 3)];
            acc[0][c] = __builtin_amdgcn_mfma_f32_16x16x32_bf16(wf, b0, acc[0][c], 0, 0, 0);
            acc[1][c] = __builtin_amdgcn_mfma_f32_16x16x32_bf16(wf, b1, acc[1][c], 0, 0, 0);
        }
    }
    // ---- epilogue 1: h = relu(acc + shift1) -> Hs (b64 writes, XOR-swizzled) ----
    int mloc0 = wave * 32 + ln;
#pragma unroll
    for (int rt = 0; rt < 2; ++rt) {
        int m = mloc0 + rt * 16;
#pragma unroll
        for (int c = 0; c < 8; ++c) {
            int n0 = c * 16 + crow4;
            float4 sh = *(const float4*)(shift1 + n0);
            float v0 = fmaxf(acc[rt][c][0] + sh.x, 0.f);
            float v1 = fmaxf(acc[rt][c][1] + sh.y, 0.f);
            float v2 = fmaxf(acc[rt][c][2] + sh.z, 0.f);
            float v3 = fmaxf(acc[rt][c][3] + sh.w, 0.f);
            int cc = n0 >> 3;
            int addr = m * 128 + (((cc ^ (m & 7)) << 3) | (n0 & 7));
            *(uint2*)&Hs[addr] = make_uint2(pack2(v0, v1), pack2(v2, v3));
        }
    }
    __syncthreads();
    // stage W2 (overwrites Ws)
    {
        const float4* srcp = (const float4*)W2;
        float4* dstp = (float4*)Ws;
#pragma unroll
        for (int i = 0; i < 8; i++) dstp[t + i * 256] = srcp[t + i * 256];
    }
    __syncthreads();

    // ---- GEMM2 (swapped): B-frags = h rows from Hs, A-frags = W2 from LDS ----
#pragma unroll
    for (int i = 0; i < 2; i++)
#pragma unroll
        for (int c = 0; c < 8; c++) acc[i][c] = (f32x4){0.f, 0.f, 0.f, 0.f};
    int m0 = mloc0, m1 = mloc0 + 16;
#pragma unroll
    for (int s = 0; s < 4; ++s) {
        short8 h0 = *(const short8*)&Hs[m0 * 128 + (((s * 4 + aq) ^ (m0 & 7)) << 3)];
        short8 h1 = *(const short8*)&Hs[m1 * 128 + (((s * 4 + aq) ^ (m1 & 7)) << 3)];
#pragma unroll
        for (int c = 0; c < 8; ++c) {
            int n = c * 16 + ln;
            short8 wf = *(const short8*)&Ws[n * 128 + (((s * 4 + aq) ^ (n & 7)) << 3)];
            acc[0][c] = __builtin_amdgcn_mfma_f32_16x16x32_bf16(wf, h0, acc[0][c], 0, 0, 0);
            acc[1][c] = __builtin_amdgcn_mfma_f32_16x16x32_bf16(wf, h1, acc[1][c], 0, 0, 0);
        }
    }
    // ---- epilogue 2: relu(acc + shift2) -> Out rows (8B runs) ----
#pragma unroll
    for (int rt = 0; rt < 2; ++rt) {
        int row = rowbase + rt * 16 + ln;
        if (row >= N_NODES) continue;
        unsigned short* op = Out + (size_t)row * 128;
#pragma unroll
        for (int c = 0; c < 8; ++c) {
            int n0 = c * 16 + crow4;
            float4 sh = *(const float4*)(shift2 + n0);
            float v0 = fmaxf(acc[rt][c][0] + sh.x, 0.f);
            float v1 = fmaxf(acc[rt][c][1] + sh.y, 0.f);
            float v2 = fmaxf(acc[rt][c][2] + sh.z, 0.f);
            float v3 = fmaxf(acc[rt][c][3] + sh.w, 0.f);
            *(uint2*)(op + n0) = make_uint2(pack2(v0, v1), pack2(v2, v3));
        }
    }
}

// ---------------- graph bounds: gs[g] = lower_bound(batch, g), gs[512] = N ----------------
__global__ void graph_bounds_kernel(const int* __restrict__ batch, int* __restrict__ gs) {
    int g = blockIdx.x * blockDim.x + threadIdx.x;
    if (g > N_GRAPHS) return;
    int lo = 0, hi = N_NODES;
    while (lo < hi) {
        int mid = (lo + hi) >> 1;
        if (batch[mid] < g) lo = mid + 1; else hi = mid;
    }
    gs[g] = lo;
}

// ---------------- segmented pool: one block (64 thr) per graph, no atomics ----------------
__global__ void pool_seg_kernel(const unsigned short* __restrict__ h, const int* __restrict__ gs,
                                float* __restrict__ hg) {
    int g = blockIdx.x, t = threadIdx.x;  // 64 threads, t owns col pair 2t,2t+1
    int s = gs[g], e = gs[g + 1];
    const u32* hp = (const u32*)h;
    float a0 = 0.f, a1 = 0.f, b0 = 0.f, b1 = 0.f, c0 = 0.f, c1 = 0.f, d0 = 0.f, d1 = 0.f;
    int r = s;
    for (; r + 4 <= e; r += 4) {
        u32 v0 = hp[(size_t)r * 64 + t];
        u32 v1 = hp[(size_t)(r + 1) * 64 + t];
        u32 v2 = hp[(size_t)(r + 2) * 64 + t];
        u32 v3 = hp[(size_t)(r + 3) * 64 + t];
        a0 += bflo(v0); a1 += bfhi(v0);
        b0 += bflo(v1); b1 += bfhi(v1);
        c0 += bflo(v2); c1 += bfhi(v2);
        d0 += bflo(v3); d1 += bfhi(v3);
    }
    for (; r < e; ++r) {
        u32 v = hp[(size_t)r * 64 + t];
        a0 += bflo(v); a1 += bfhi(v);
    }
    float2 o = make_float2(a0 + b0 + c0 + d0, a1 + b1 + c1 + d1);
    *(float2*)&hg[g * 128 + t * 2] = o;
}

// ---------------- head ----------------
__global__ void head_kernel(const float* __restrict__ hg, const float* __restrict__ l1w,
                            const float* __restrict__ l1b, const float* __restrict__ l2w,
                            const float* __restrict__ l2b, float* __restrict__ out) {
    __shared__ float row[128];
    int g = blockIdx.x, t = threadIdx.x;  // 64 threads
    *(float2*)&row[t * 2] = *(const float2*)&hg[g * 128 + t * 2];
    __syncthreads();
    float a = l1b[t];
    for (int k = 0; k < 128; k++) a = fmaf(row[k], l1w[k * 64 + t], a);
    a = fmaxf(a, 0.f);
    float p = a * l2w[t];
    for (int d = 32; d; d >>= 1) p += __shfl_down(p, d);
    if (t == 0) out[g] = 1.f / (1.f + expf(-(p + l2b[0])));
}

extern "C" void kernel_launch(void* const* d_in, const int* in_sizes, int n_in,
                              void* d_out, int out_size, void* d_ws, size_t ws_size,
                              hipStream_t stream) {
    (void)in_sizes; (void)n_in; (void)out_size; (void)ws_size;
    const float* x = (const float*)d_in[0];
    const int* ei = (const int*)d_in[1];
    const int* batch = (const int*)d_in[2];
    WArgs6 wa;
    for (int i = 0; i < 3; i++) {
        int base = 3 + i * 8;
        wa.a[i * 2] = WArgs{(const float*)d_in[base + 0], (const float*)d_in[base + 1],
                            (const float*)d_in[base + 2], (const float*)d_in[base + 3],
                            (const float*)d_in[base + 4], (const float*)d_in[base + 5],
                            (i == 0) ? IN_DIM : DIM_H, 1};
        wa.a[i * 2 + 1] = WArgs{(const float*)d_in[base + 6], (const float*)d_in[base + 7],
                                nullptr, nullptr, nullptr, nullptr, DIM_H, 0};
    }
    const float* l1w = (const float*)d_in[27];
    const float* l1b = (const float*)d_in[28];
    const float* l2w = (const float*)d_in[29];
    const float* l2b = (const float*)d_in[30];

    char* ws = (char*)d_ws;
    size_t off = 0;
    auto alloc = [&](size_t bytes) -> void* {
        void* p = ws + off;
        off += (bytes + 511) & ~(size_t)511;
        return p;
    };
    unsigned short* A = (unsigned short*)alloc((size_t)N_NODES * 128 * 2);
    unsigned short* B = (unsigned short*)alloc((size_t)N_NODES * 128 * 2);
    float* hg = (float*)alloc((size_t)N_GRAPHS * 128 * 4);
    unsigned short* Wt = (unsigned short*)alloc((size_t)6 * 16384 * 2);
    float* shift = (float*)alloc(6 * 128 * 4);
    int* counts = (int*)alloc((size_t)N_NODES * 4);
    int* offsets = (int*)alloc((size_t)N_NODES * 4);
    int* perm = (int*)alloc((size_t)N_EDGES * 4);
    uint2* ebuf = (uint2*)alloc((size_t)N_EDGES * 8);
    int* bucket_count = (int*)alloc((NBUCK + 1) * 4);
    int* bucket_base = (int*)alloc((NBUCK + 1) * 4);
    int* bucket_cursor = (int*)alloc(NBUCK * 4);
    int* gs = (int*)alloc((N_GRAPHS + 1) * 4);

    const int* src = ei;
    const int* dst = ei + N_EDGES;

    hipMemsetAsync(bucket_count, 0, (NBUCK + 1) * 4, stream);
    bucket_count_kernel<<<256, 256, 0, stream>>>(dst, bucket_count);
    bucket_scan_kernel<<<1, 128, 0, stream>>>(bucket_count, bucket_base, bucket_cursor);
    bucket_scatter_kernel<<<256, 256, 0, stream>>>(src, dst, bucket_cursor, ebuf);
    bucket_build_kernel<<<NBUCK, 512, 0, stream>>>(ebuf, bucket_base, counts, offsets, perm);
    prep_w_kernel<<<48, 256, 0, stream>>>(wa, Wt, shift);
    pad_x_kernel<<<(N_NODES * 64 + 255) / 256, 256, 0, stream>>>(x, A);
    graph_bounds_kernel<<<3, 256, 0, stream>>>(batch, gs);

    const int GB = (N_NODES + 127) / 128;  // 391
    for (int l = 0; l < 3; ++l) {
        aggregate_kernel<<<(N_NODES * 64 + 255) / 256, 256, 0, stream>>>(A, B, offsets, counts, perm);
        conv_fused_kernel<<<GB, 256, 0, stream>>>(
            B, Wt + (size_t)(l * 2) * 16384, shift + (l * 2) * 128,
            Wt + (size_t)(l * 2 + 1) * 16384, shift + (l * 2 + 1) * 128, A);
    }
    pool_seg_kernel<<<N_GRAPHS, 64, 0, stream>>>(A, gs, hg);
    head_kernel<<<N_GRAPHS, 64, 0, stream>>>(hg, l1w, l1b, l2w, l2b, (float*)d_out);
}